// Round 4
// baseline (443.062 us; speedup 1.0000x reference)
//
#include <hip/hip_runtime.h>

#define DEVINL __device__ __forceinline__

typedef unsigned short u16;
typedef float f32x4 __attribute__((ext_vector_type(4)));
typedef __bf16 bf16x8 __attribute__((ext_vector_type(8)));

constexpr int N_ = 1024, B_ = 4, C_ = 1024, H_ = 8, D_ = 128;
constexpr int NB = N_ * B_;   // 4096 rows
constexpr int BH = B_ * H_;   // 32 head-batches

// ---------- helpers ----------
DEVINL u16 f2bf(float f) {            // RNE f32 -> bf16 (inputs finite)
  unsigned u = __builtin_bit_cast(unsigned, f);
  u += 0x7fffu + ((u >> 16) & 1u);
  return (u16)(u >> 16);
}
DEVINL float bf2f(u16 v) { return __builtin_bit_cast(float, ((unsigned)v) << 16); }

typedef __attribute__((address_space(1))) void gv_t;
typedef __attribute__((address_space(3))) void lv_t;
DEVINL void gload16(const void* g, void* l) {   // async global->LDS, 16B/lane
  __builtin_amdgcn_global_load_lds((gv_t*)(unsigned long long)g,
                                   (lv_t*)(unsigned)(unsigned long long)l, 16, 0, 0);
}
DEVINL bf16x8 ld_frag(const u16* p) { return *(const bf16x8*)p; }
DEVINL f32x4 mfma16(bf16x8 a, bf16x8 b, f32x4 c) {
  return __builtin_amdgcn_mfma_f32_16x16x32_bf16(a, b, c, 0, 0, 0);
}

// ---------- K0: fp32 -> bf16 convert ----------
struct ConvArgs { const float* s[10]; u16* d[10]; int n[10]; };

__global__ __launch_bounds__(256) void k_convert(ConvArgs a) {
  const int which = blockIdx.y;
  const int i = (blockIdx.x * 256 + threadIdx.x) * 8;
  if (i >= a.n[which]) return;
  const float* s = a.s[which] + i;
  float4 v0 = *(const float4*)s;
  float4 v1 = *(const float4*)(s + 4);
  union { uint4 v; u16 r[8]; } u;
  u.r[0] = f2bf(v0.x); u.r[1] = f2bf(v0.y); u.r[2] = f2bf(v0.z); u.r[3] = f2bf(v0.w);
  u.r[4] = f2bf(v1.x); u.r[5] = f2bf(v1.y); u.r[6] = f2bf(v1.z); u.r[7] = f2bf(v1.w);
  *(uint4*)(a.d[which] + i) = u.v;
}

// ---------- K1: projection GEMM + fused L2-norm, XCD-chunked swizzle ----------
// Y[r,d] = sum_c X[r,c] * W[d,c]. grid 1280 blocks (8 d-tiles x 32 r-tiles x 5
// tensors), remapped so each XCD owns a contiguous chunk: the 8 d-tile blocks
// sharing an X row-panel colocate (panel read once/XCD) and W (2MB) stays L2-hot.
struct ProjArgs { const u16* X[5]; const u16* W[5]; u16* O[5]; };

__global__ __launch_bounds__(256) void k_proj(ProjArgs a) {
  __shared__ u16 lA[128 * 64];
  __shared__ u16 lB[128 * 64];
  __shared__ float lred[128][2];
  const int tid = threadIdx.x, w = tid >> 6, lane = tid & 63;
  const int qd = lane >> 4, m16 = lane & 15;
  const int wr = w >> 1, wc = w & 1;
  // bijective XCD swizzle: nwg = 1280, 1280 % 8 == 0
  const int flat = blockIdx.x + (blockIdx.y << 3) + (blockIdx.z << 8);
  const int swz = (flat & 7) * 160 + (flat >> 3);
  const int bz = swz >> 8, rem = swz & 255, by = rem >> 3, bx = rem & 7;
  const int r0 = by * 128, d0 = bx * 128;
  const u16* __restrict__ X = a.X[bz];
  const u16* __restrict__ W = a.W[bz];
  u16* __restrict__ O = a.O[bz];
  const bool donorm = bz < 4;

  f32x4 acc[4][4];
  const f32x4 fz = {0.f, 0.f, 0.f, 0.f};
#pragma unroll
  for (int i = 0; i < 4; ++i)
#pragma unroll
    for (int j = 0; j < 4; ++j) acc[i][j] = fz;

  for (int k0 = 0; k0 < C_; k0 += 64) {
    __syncthreads();
#pragma unroll
    for (int i = 0; i < 4; ++i) {
      int p = i * 256 + tid, row = p >> 3, cp = p & 7, cl = cp ^ (row & 7);
      gload16(X + (size_t)(r0 + row) * C_ + k0 + cl * 8, &lA[p * 8]);
    }
#pragma unroll
    for (int i = 0; i < 4; ++i) {
      int p = i * 256 + tid, row = p >> 3, cp = p & 7, cl = cp ^ (row & 7);
      gload16(W + (size_t)(d0 + row) * C_ + k0 + cl * 8, &lB[p * 8]);
    }
    __syncthreads();
#pragma unroll
    for (int ks = 0; ks < 2; ++ks) {
      bf16x8 af[4], bfr[4];
#pragma unroll
      for (int t = 0; t < 4; ++t) {
        int row = wr * 64 + t * 16 + m16;
        af[t] = ld_frag(&lA[row * 64 + (((ks * 4 + qd) ^ (row & 7)) * 8)]);
        int col = wc * 64 + t * 16 + m16;
        bfr[t] = ld_frag(&lB[col * 64 + (((ks * 4 + qd) ^ (col & 7)) * 8)]);
      }
#pragma unroll
      for (int rt = 0; rt < 4; ++rt)
#pragma unroll
        for (int ct = 0; ct < 4; ++ct)
          acc[rt][ct] = mfma16(af[rt], bfr[ct], acc[rt][ct]);
    }
  }
  // fused L2-norm over the 128-col (= head dim) tile
  if (donorm) {
    float s[4][4];
#pragma unroll
    for (int rt = 0; rt < 4; ++rt)
#pragma unroll
      for (int rg = 0; rg < 4; ++rg) {
        float t = 0.f;
#pragma unroll
        for (int ct = 0; ct < 4; ++ct) t += acc[rt][ct][rg] * acc[rt][ct][rg];
        s[rt][rg] = t;
      }
#pragma unroll
    for (int off = 1; off < 16; off <<= 1)
#pragma unroll
      for (int rt = 0; rt < 4; ++rt)
#pragma unroll
        for (int rg = 0; rg < 4; ++rg) s[rt][rg] += __shfl_xor(s[rt][rg], off);
    if (m16 == 0) {
#pragma unroll
      for (int rt = 0; rt < 4; ++rt)
#pragma unroll
        for (int rg = 0; rg < 4; ++rg)
          lred[wr * 64 + rt * 16 + qd * 4 + rg][wc] = s[rt][rg];
    }
  }
  __syncthreads();
  float inv[4][4];
#pragma unroll
  for (int rt = 0; rt < 4; ++rt)
#pragma unroll
    for (int rg = 0; rg < 4; ++rg) {
      if (donorm) {
        int row = wr * 64 + rt * 16 + qd * 4 + rg;
        inv[rt][rg] = rsqrtf(lred[row][0] + lred[row][1]);
      } else inv[rt][rg] = 1.0f;
    }
  // epilogue: rows r = n*B+b ; cols = h*128+d ; write (B,H,N,D) bf16
#pragma unroll
  for (int rt = 0; rt < 4; ++rt)
#pragma unroll
    for (int ct = 0; ct < 4; ++ct)
#pragma unroll
      for (int rg = 0; rg < 4; ++rg) {
        int row = r0 + wr * 64 + rt * 16 + qd * 4 + rg;
        int col = d0 + wc * 64 + ct * 16 + m16;
        int n = row >> 2, b = row & 3, h = col >> 7, d = col & 127;
        O[(((size_t)(b * H_ + h)) * N_ + n) * D_ + d] = f2bf(acc[rt][ct][rg] * inv[rt][rg]);
      }
}

// ---------- K3: v (B,H,N,D) -> v_t (B,H,D,N) ----------
__global__ __launch_bounds__(256) void k_transpose(const u16* __restrict__ v,
                                                   u16* __restrict__ vt) {
  __shared__ u16 tile[128][65];
  const int bh = blockIdx.y, n0 = blockIdx.x * 64;
  const u16* src = v + (size_t)bh * N_ * D_;
  u16* dst = vt + (size_t)bh * D_ * N_;
  union U8 { uint4 v; u16 s[8]; };
#pragma unroll
  for (int it = 0; it < 4; ++it) {
    int c = it * 256 + threadIdx.x;
    int n = c >> 4, dc = (c & 15) * 8;
    U8 u; u.v = *(const uint4*)(src + (size_t)(n0 + n) * D_ + dc);
#pragma unroll
    for (int j = 0; j < 8; ++j) tile[dc + j][n] = u.s[j];
  }
  __syncthreads();
#pragma unroll
  for (int it = 0; it < 4; ++it) {
    int c = it * 256 + threadIdx.x;
    int d = c >> 3, nc = (c & 7) * 8;
    U8 u;
#pragma unroll
    for (int j = 0; j < 8; ++j) u.s[j] = tile[d][nc + j];
    *(uint4*)(dst + (size_t)d * N_ + n0 + nc) = u.v;
  }
}

// ---------- K4: fused stats + emit + PV, 512 threads / 8 waves ----------
// One block owns a 32-row n-strip of one (b,h); 8 waves each own a 16-row
// m-slice per 128-m tile. K IS LDS-staged (R3 showed direct-global loads are
// latency-bound), but SINGLE-buffered: lK 64KB + lP 8.5KB + lred 2KB ~= 75KB
// < 80KB, so with VGPR<=128 (launch_bounds 512,4) we get 2 blocks/CU and
// barrier stalls of one block overlap compute/staging of the other.
__global__ __launch_bounds__(512, 4) void k_attn(const u16* __restrict__ qr,
                                                 const u16* __restrict__ kr,
                                                 const u16* __restrict__ qc,
                                                 const u16* __restrict__ kc,
                                                 const u16* __restrict__ vt,
                                                 float* __restrict__ out0,
                                                 float* __restrict__ out1) {
  __shared__ u16 lK[2][128 * 128];   // 64 KB: [ty] (128m x 128d), single-buffered
  __shared__ u16 lP[32 * 136];       // 8.5 KB attn bf16, [n][m] A-layout (pad 8)
  __shared__ float lred[2][8][32];   // 2 KB denominator partials
  const int flat = blockIdx.x + (blockIdx.y << 5);
  const int xcd = flat & 7, kk = flat >> 3;
  const int bh = (xcd << 2) + (kk >> 5);
  const int n0 = (kk & 31) * 32;
  const int b = bh >> 3, h = bh & 7;
  const size_t base = (size_t)bh * N_ * D_;
  const int tid = threadIdx.x, w = tid >> 6, lane = tid & 63;
  const int qd = lane >> 4, m16 = lane & 15;
  const u16* ksrc[2] = {kr, kc};

  // Q fragments (B-operand layout): [type][ct 2][ks 4] = 64 VGPR
  bf16x8 qf[2][2][4];
#pragma unroll
  for (int ct = 0; ct < 2; ++ct)
#pragma unroll
    for (int ks = 0; ks < 4; ++ks) {
      size_t ro = base + (size_t)(n0 + ct * 16 + m16) * D_ + ks * 32 + qd * 8;
      qf[0][ct][ks] = ld_frag(qr + ro);
      qf[1][ct][ks] = ld_frag(qc + ro);
    }

  // packed exp(S) bf16 held in registers for the whole strip:
  // [type][mt][ct] -> 4 bf16 (uint2) = 64 VGPRs total
  uint2 pst[2][8][2];
  float psum[2][2] = {{0.f, 0.f}, {0.f, 0.f}};
  const f32x4 fz = {0.f, 0.f, 0.f, 0.f};

  // ---- loop 1: stage K tile, S once, exp -> regs, accumulate denominators ----
#pragma unroll
  for (int mt = 0; mt < 8; ++mt) {
    const int m0 = mt * 128;
    __syncthreads();  // previous tile's readers done -> lK reusable
#pragma unroll
    for (int ty = 0; ty < 2; ++ty)
#pragma unroll
      for (int i = 0; i < 4; ++i) {
        int p = i * 512 + tid, row = p >> 4, cp = p & 15, cl = cp ^ (row & 15);
        gload16(ksrc[ty] + base + (size_t)(m0 + row) * D_ + cl * 8, &lK[ty][p * 8]);
      }
    __syncthreads();  // drains gload_lds (vmcnt) -> tile visible
    const int mrow = w * 16 + m16;
#pragma unroll
    for (int ty = 0; ty < 2; ++ty) {
      bf16x8 af[4];
#pragma unroll
      for (int ks = 0; ks < 4; ++ks)
        af[ks] = ld_frag(&lK[ty][mrow * 128 + (((ks * 4 + qd) ^ (mrow & 15)) * 8)]);
#pragma unroll
      for (int ct = 0; ct < 2; ++ct) {
        f32x4 acc = fz;
#pragma unroll
        for (int ks = 0; ks < 4; ++ks) acc = mfma16(af[ks], qf[ty][ct][ks], acc);
        union { uint2 u; u16 s[4]; } pk;
        float loc = 0.f;
#pragma unroll
        for (int rg = 0; rg < 4; ++rg) {
          float e = __expf(acc[rg]);
          loc += e;
          pk.s[rg] = f2bf(e);
        }
        psum[ty][ct] += loc;
        pst[ty][mt][ct] = pk.u;
      }
    }
  }

  // ---- denominator reduction: over qd (shfl) then over 8 waves (LDS) ----
#pragma unroll
  for (int ty = 0; ty < 2; ++ty)
#pragma unroll
    for (int ct = 0; ct < 2; ++ct) {
      psum[ty][ct] += __shfl_xor(psum[ty][ct], 16);
      psum[ty][ct] += __shfl_xor(psum[ty][ct], 32);
    }
  __syncthreads();  // loop-1 lK readers done (also orders lred below)
  if (qd == 0) {
#pragma unroll
    for (int ty = 0; ty < 2; ++ty)
#pragma unroll
      for (int ct = 0; ct < 2; ++ct) lred[ty][w][ct * 16 + m16] = psum[ty][ct];
  }
  __syncthreads();
  float il[2][2];
#pragma unroll
  for (int ty = 0; ty < 2; ++ty)
#pragma unroll
    for (int ct = 0; ct < 2; ++ct) {
      int n = ct * 16 + m16;
      float s = 0.f;
#pragma unroll
      for (int ww = 0; ww < 8; ++ww) s += lred[ty][ww][n];
      il[ty][ct] = 0.5f / s;
    }

  f32x4 xacc[2] = {fz, fz};
  float* attn = out1 + (size_t)bh * N_ * N_;
  const u16* vtb = vt + (size_t)bh * D_ * N_ + (size_t)(w * 16 + m16) * N_;

  // ---- loop 2: normalize, store attn, PV (single lP, 2 barriers/tile) ----
#pragma unroll
  for (int mt = 0; mt < 8; ++mt) {
    const int m0 = mt * 128;
#pragma unroll
    for (int ct = 0; ct < 2; ++ct) {
      union { uint2 u; u16 s[4]; } ur, uc, pk;
      ur.u = pst[0][mt][ct];
      uc.u = pst[1][mt][ct];
      f32x4 pv;
#pragma unroll
      for (int rg = 0; rg < 4; ++rg) {
        pv[rg] = bf2f(ur.s[rg]) * il[0][ct] + bf2f(uc.s[rg]) * il[1][ct];
        pk.s[rg] = f2bf(pv[rg]);
      }
      const int nrow = n0 + ct * 16 + m16;
      const int mcol = m0 + w * 16 + qd * 4;
      *(f32x4*)(attn + (size_t)nrow * N_ + mcol) = pv;
      *(uint2*)&lP[(ct * 16 + m16) * 136 + w * 16 + qd * 4] = pk.u;
    }
    __syncthreads();  // lP tile complete
#pragma unroll
    for (int ks = 0; ks < 4; ++ks) {
      bf16x8 pa[2];
#pragma unroll
      for (int ct = 0; ct < 2; ++ct)
        pa[ct] = ld_frag(&lP[(ct * 16 + m16) * 136 + ks * 32 + qd * 8]);
      bf16x8 vb = ld_frag(vtb + m0 + ks * 32 + qd * 8);
#pragma unroll
      for (int ct = 0; ct < 2; ++ct)
        xacc[ct] = mfma16(pa[ct], vb, xacc[ct]);
    }
    __syncthreads();  // lP readers done -> next tile may overwrite
  }
  // epilogue: x -> out0 (N,B,C)
#pragma unroll
  for (int ct = 0; ct < 2; ++ct)
#pragma unroll
    for (int rg = 0; rg < 4; ++rg) {
      int n = n0 + ct * 16 + qd * 4 + rg;
      int d = w * 16 + m16;
      out0[((size_t)n * B_ + b) * C_ + h * 128 + d] = xacc[ct][rg];
    }
}

// ---------- launch ----------
extern "C" void kernel_launch(void* const* d_in, const int* in_sizes, int n_in,
                              void* d_out, int out_size, void* d_ws, size_t ws_size,
                              hipStream_t stream) {
  (void)in_sizes; (void)n_in; (void)out_size; (void)ws_size;
  const float* in_f[10];
  for (int i = 0; i < 10; ++i) in_f[i] = (const float*)d_in[i];

  u16* ws = (u16*)d_ws;
  u16* Xc[5], *Wc[5], *P[5];
  for (int i = 0; i < 5; ++i) Xc[i] = ws + (size_t)i * NB * C_;
  u16* wbase = ws + (size_t)5 * NB * C_;
  for (int i = 0; i < 5; ++i) Wc[i] = wbase + (size_t)i * C_ * C_;
  u16* pbase = wbase + (size_t)5 * C_ * C_;
  for (int i = 0; i < 5; ++i) P[i] = pbase + (size_t)i * BH * N_ * D_;
  u16* vt = pbase + (size_t)5 * BH * N_ * D_;

  float* out0 = (float*)d_out;
  float* out1 = out0 + (size_t)N_ * B_ * C_;

  ConvArgs ca;
  for (int i = 0; i < 5; ++i) { ca.s[i] = in_f[i];     ca.d[i] = Xc[i];  ca.n[i] = NB * C_; }
  for (int i = 0; i < 5; ++i) { ca.s[5+i] = in_f[5+i]; ca.d[5+i] = Wc[i]; ca.n[5+i] = C_ * C_; }
  k_convert<<<dim3(2048, 10), 256, 0, stream>>>(ca);

  ProjArgs pa;
  for (int i = 0; i < 5; ++i) { pa.X[i] = Xc[i]; pa.W[i] = Wc[i]; pa.O[i] = P[i]; }
  k_proj<<<dim3(C_ / 128, NB / 128, 5), 256, 0, stream>>>(pa);

  k_transpose<<<dim3(N_ / 64, BH), 256, 0, stream>>>(P[4], vt);

  k_attn<<<dim3(N_ / 32, BH), 512, 0, stream>>>(P[0], P[1], P[2], P[3], vt, out0, out1);
}

// Round 5
// 402.087 us; speedup vs baseline: 1.1019x; 1.1019x over previous
//
#include <hip/hip_runtime.h>

#define DEVINL __device__ __forceinline__

typedef unsigned short u16;
typedef float f32x4 __attribute__((ext_vector_type(4)));
typedef __bf16 bf16x8 __attribute__((ext_vector_type(8)));

constexpr int N_ = 1024, B_ = 4, C_ = 1024, H_ = 8, D_ = 128;
constexpr int NB = N_ * B_;   // 4096 rows
constexpr int BH = B_ * H_;   // 32 head-batches

// ---------- helpers ----------
DEVINL u16 f2bf(float f) {            // RNE f32 -> bf16 (inputs finite)
  unsigned u = __builtin_bit_cast(unsigned, f);
  u += 0x7fffu + ((u >> 16) & 1u);
  return (u16)(u >> 16);
}
DEVINL float bf2f(u16 v) { return __builtin_bit_cast(float, ((unsigned)v) << 16); }

typedef __attribute__((address_space(1))) void gv_t;
typedef __attribute__((address_space(3))) void lv_t;
DEVINL void gload16(const void* g, void* l) {   // async global->LDS, 16B/lane
  __builtin_amdgcn_global_load_lds((gv_t*)(unsigned long long)g,
                                   (lv_t*)(unsigned)(unsigned long long)l, 16, 0, 0);
}
DEVINL bf16x8 ld_frag(const u16* p) { return *(const bf16x8*)p; }
DEVINL f32x4 mfma16(bf16x8 a, bf16x8 b, f32x4 c) {
  return __builtin_amdgcn_mfma_f32_16x16x32_bf16(a, b, c, 0, 0, 0);
}

// ---------- K0: fp32 -> bf16 convert ----------
struct ConvArgs { const float* s[10]; u16* d[10]; int n[10]; };

__global__ __launch_bounds__(256) void k_convert(ConvArgs a) {
  const int which = blockIdx.y;
  const int i = (blockIdx.x * 256 + threadIdx.x) * 8;
  if (i >= a.n[which]) return;
  const float* s = a.s[which] + i;
  float4 v0 = *(const float4*)s;
  float4 v1 = *(const float4*)(s + 4);
  union { uint4 v; u16 r[8]; } u;
  u.r[0] = f2bf(v0.x); u.r[1] = f2bf(v0.y); u.r[2] = f2bf(v0.z); u.r[3] = f2bf(v0.w);
  u.r[4] = f2bf(v1.x); u.r[5] = f2bf(v1.y); u.r[6] = f2bf(v1.z); u.r[7] = f2bf(v1.w);
  *(uint4*)(a.d[which] + i) = u.v;
}

// ---------- K1: projection GEMM + fused L2-norm, XCD-chunked swizzle ----------
// Y[r,d] = sum_c X[r,c] * W[d,c]. grid 1280 blocks (8 d-tiles x 32 r-tiles x 5
// tensors), remapped so each XCD owns a contiguous chunk: the 8 d-tile blocks
// sharing an X row-panel colocate (panel read once/XCD) and W (2MB) stays L2-hot.
struct ProjArgs { const u16* X[5]; const u16* W[5]; u16* O[5]; };

__global__ __launch_bounds__(256) void k_proj(ProjArgs a) {
  __shared__ u16 lA[128 * 64];
  __shared__ u16 lB[128 * 64];
  __shared__ float lred[128][2];
  const int tid = threadIdx.x, w = tid >> 6, lane = tid & 63;
  const int qd = lane >> 4, m16 = lane & 15;
  const int wr = w >> 1, wc = w & 1;
  // bijective XCD swizzle: nwg = 1280, 1280 % 8 == 0
  const int flat = blockIdx.x + (blockIdx.y << 3) + (blockIdx.z << 8);
  const int swz = (flat & 7) * 160 + (flat >> 3);
  const int bz = swz >> 8, rem = swz & 255, by = rem >> 3, bx = rem & 7;
  const int r0 = by * 128, d0 = bx * 128;
  const u16* __restrict__ X = a.X[bz];
  const u16* __restrict__ W = a.W[bz];
  u16* __restrict__ O = a.O[bz];
  const bool donorm = bz < 4;

  f32x4 acc[4][4];
  const f32x4 fz = {0.f, 0.f, 0.f, 0.f};
#pragma unroll
  for (int i = 0; i < 4; ++i)
#pragma unroll
    for (int j = 0; j < 4; ++j) acc[i][j] = fz;

  for (int k0 = 0; k0 < C_; k0 += 64) {
    __syncthreads();
#pragma unroll
    for (int i = 0; i < 4; ++i) {
      int p = i * 256 + tid, row = p >> 3, cp = p & 7, cl = cp ^ (row & 7);
      gload16(X + (size_t)(r0 + row) * C_ + k0 + cl * 8, &lA[p * 8]);
    }
#pragma unroll
    for (int i = 0; i < 4; ++i) {
      int p = i * 256 + tid, row = p >> 3, cp = p & 7, cl = cp ^ (row & 7);
      gload16(W + (size_t)(d0 + row) * C_ + k0 + cl * 8, &lB[p * 8]);
    }
    __syncthreads();
#pragma unroll
    for (int ks = 0; ks < 2; ++ks) {
      bf16x8 af[4], bfr[4];
#pragma unroll
      for (int t = 0; t < 4; ++t) {
        int row = wr * 64 + t * 16 + m16;
        af[t] = ld_frag(&lA[row * 64 + (((ks * 4 + qd) ^ (row & 7)) * 8)]);
        int col = wc * 64 + t * 16 + m16;
        bfr[t] = ld_frag(&lB[col * 64 + (((ks * 4 + qd) ^ (col & 7)) * 8)]);
      }
#pragma unroll
      for (int rt = 0; rt < 4; ++rt)
#pragma unroll
        for (int ct = 0; ct < 4; ++ct)
          acc[rt][ct] = mfma16(af[rt], bfr[ct], acc[rt][ct]);
    }
  }
  // fused L2-norm over the 128-col (= head dim) tile
  if (donorm) {
    float s[4][4];
#pragma unroll
    for (int rt = 0; rt < 4; ++rt)
#pragma unroll
      for (int rg = 0; rg < 4; ++rg) {
        float t = 0.f;
#pragma unroll
        for (int ct = 0; ct < 4; ++ct) t += acc[rt][ct][rg] * acc[rt][ct][rg];
        s[rt][rg] = t;
      }
#pragma unroll
    for (int off = 1; off < 16; off <<= 1)
#pragma unroll
      for (int rt = 0; rt < 4; ++rt)
#pragma unroll
        for (int rg = 0; rg < 4; ++rg) s[rt][rg] += __shfl_xor(s[rt][rg], off);
    if (m16 == 0) {
#pragma unroll
      for (int rt = 0; rt < 4; ++rt)
#pragma unroll
        for (int rg = 0; rg < 4; ++rg)
          lred[wr * 64 + rt * 16 + qd * 4 + rg][wc] = s[rt][rg];
    }
  }
  __syncthreads();
  float inv[4][4];
#pragma unroll
  for (int rt = 0; rt < 4; ++rt)
#pragma unroll
    for (int rg = 0; rg < 4; ++rg) {
      if (donorm) {
        int row = wr * 64 + rt * 16 + qd * 4 + rg;
        inv[rt][rg] = rsqrtf(lred[row][0] + lred[row][1]);
      } else inv[rt][rg] = 1.0f;
    }
  // epilogue: rows r = n*B+b ; cols = h*128+d ; write (B,H,N,D) bf16
#pragma unroll
  for (int rt = 0; rt < 4; ++rt)
#pragma unroll
    for (int ct = 0; ct < 4; ++ct)
#pragma unroll
      for (int rg = 0; rg < 4; ++rg) {
        int row = r0 + wr * 64 + rt * 16 + qd * 4 + rg;
        int col = d0 + wc * 64 + ct * 16 + m16;
        int n = row >> 2, b = row & 3, h = col >> 7, d = col & 127;
        O[(((size_t)(b * H_ + h)) * N_ + n) * D_ + d] = f2bf(acc[rt][ct][rg] * inv[rt][rg]);
      }
}

// ---------- K3: v (B,H,N,D) -> v_t (B,H,D,N) ----------
__global__ __launch_bounds__(256) void k_transpose(const u16* __restrict__ v,
                                                   u16* __restrict__ vt) {
  __shared__ u16 tile[128][65];
  const int bh = blockIdx.y, n0 = blockIdx.x * 64;
  const u16* src = v + (size_t)bh * N_ * D_;
  u16* dst = vt + (size_t)bh * D_ * N_;
  union U8 { uint4 v; u16 s[8]; };
#pragma unroll
  for (int it = 0; it < 4; ++it) {
    int c = it * 256 + threadIdx.x;
    int n = c >> 4, dc = (c & 15) * 8;
    U8 u; u.v = *(const uint4*)(src + (size_t)(n0 + n) * D_ + dc);
#pragma unroll
    for (int j = 0; j < 8; ++j) tile[dc + j][n] = u.s[j];
  }
  __syncthreads();
#pragma unroll
  for (int it = 0; it < 4; ++it) {
    int c = it * 256 + threadIdx.x;
    int d = c >> 3, nc = (c & 7) * 8;
    U8 u;
#pragma unroll
    for (int j = 0; j < 8; ++j) u.s[j] = tile[d][nc + j];
    *(uint4*)(dst + (size_t)d * N_ + n0 + nc) = u.v;
  }
}

// ---------- K4: fused stats + emit + PV, 512 threads / 8 waves ----------
// One block owns a 32-row n-strip of one (b,h); 8 waves each own a 16-row
// m-slice per 128-m tile. K is LDS-staged (R3: direct-global is latency-bound)
// but SINGLE-buffered: lK 64KB + lP 8.5KB + lred 2KB = 74.5KB -> 2 blocks/CU.
// launch_bounds(512,2) is the empirically-calibrated setting that yields
// ~112 VGPR WITHOUT spill ((512,4) forced 64 VGPR -> scratch disaster, R4).
__global__ __launch_bounds__(512, 2) void k_attn(const u16* __restrict__ qr,
                                                 const u16* __restrict__ kr,
                                                 const u16* __restrict__ qc,
                                                 const u16* __restrict__ kc,
                                                 const u16* __restrict__ vt,
                                                 float* __restrict__ out0,
                                                 float* __restrict__ out1) {
  __shared__ u16 lK[2][128 * 128];   // 64 KB: [ty] (128m x 128d), single-buffered
  __shared__ u16 lP[32 * 136];       // 8.5 KB attn bf16, [n][m] A-layout (pad 8)
  __shared__ float lred[2][8][32];   // 2 KB denominator partials
  const int flat = blockIdx.x + (blockIdx.y << 5);
  const int xcd = flat & 7, kk = flat >> 3;
  const int bh = (xcd << 2) + (kk >> 5);
  const int n0 = (kk & 31) * 32;
  const int b = bh >> 3, h = bh & 7;
  const size_t base = (size_t)bh * N_ * D_;
  const int tid = threadIdx.x, w = tid >> 6, lane = tid & 63;
  const int qd = lane >> 4, m16 = lane & 15;
  const u16* ksrc[2] = {kr, kc};

  // Q fragments (B-operand layout): [type][ct 2][ks 4] = 64 VGPR
  bf16x8 qf[2][2][4];
#pragma unroll
  for (int ct = 0; ct < 2; ++ct)
#pragma unroll
    for (int ks = 0; ks < 4; ++ks) {
      size_t ro = base + (size_t)(n0 + ct * 16 + m16) * D_ + ks * 32 + qd * 8;
      qf[0][ct][ks] = ld_frag(qr + ro);
      qf[1][ct][ks] = ld_frag(qc + ro);
    }

  // packed exp(S) bf16 held in registers for the whole strip:
  // [type][mt][ct] -> 4 bf16 (uint2) = 64 VGPRs total
  uint2 pst[2][8][2];
  float psum[2][2] = {{0.f, 0.f}, {0.f, 0.f}};
  const f32x4 fz = {0.f, 0.f, 0.f, 0.f};

  // ---- loop 1: stage K tile, S once, exp -> regs, accumulate denominators ----
#pragma unroll
  for (int mt = 0; mt < 8; ++mt) {
    const int m0 = mt * 128;
    __syncthreads();  // previous tile's readers done -> lK reusable
#pragma unroll
    for (int ty = 0; ty < 2; ++ty)
#pragma unroll
      for (int i = 0; i < 4; ++i) {
        int p = i * 512 + tid, row = p >> 4, cp = p & 15, cl = cp ^ (row & 15);
        gload16(ksrc[ty] + base + (size_t)(m0 + row) * D_ + cl * 8, &lK[ty][p * 8]);
      }
    __syncthreads();  // drains gload_lds (vmcnt) -> tile visible
    const int mrow = w * 16 + m16;
#pragma unroll
    for (int ty = 0; ty < 2; ++ty) {
      bf16x8 af[4];
#pragma unroll
      for (int ks = 0; ks < 4; ++ks)
        af[ks] = ld_frag(&lK[ty][mrow * 128 + (((ks * 4 + qd) ^ (mrow & 15)) * 8)]);
#pragma unroll
      for (int ct = 0; ct < 2; ++ct) {
        f32x4 acc = fz;
#pragma unroll
        for (int ks = 0; ks < 4; ++ks) acc = mfma16(af[ks], qf[ty][ct][ks], acc);
        union { uint2 u; u16 s[4]; } pk;
        float loc = 0.f;
#pragma unroll
        for (int rg = 0; rg < 4; ++rg) {
          float e = __expf(acc[rg]);
          loc += e;
          pk.s[rg] = f2bf(e);
        }
        psum[ty][ct] += loc;
        pst[ty][mt][ct] = pk.u;
      }
    }
  }

  // ---- denominator reduction: over qd (shfl) then over 8 waves (LDS) ----
#pragma unroll
  for (int ty = 0; ty < 2; ++ty)
#pragma unroll
    for (int ct = 0; ct < 2; ++ct) {
      psum[ty][ct] += __shfl_xor(psum[ty][ct], 16);
      psum[ty][ct] += __shfl_xor(psum[ty][ct], 32);
    }
  __syncthreads();  // loop-1 lK readers done (also orders lred below)
  if (qd == 0) {
#pragma unroll
    for (int ty = 0; ty < 2; ++ty)
#pragma unroll
      for (int ct = 0; ct < 2; ++ct) lred[ty][w][ct * 16 + m16] = psum[ty][ct];
  }
  __syncthreads();
  float il[2][2];
#pragma unroll
  for (int ty = 0; ty < 2; ++ty)
#pragma unroll
    for (int ct = 0; ct < 2; ++ct) {
      int n = ct * 16 + m16;
      float s = 0.f;
#pragma unroll
      for (int ww = 0; ww < 8; ++ww) s += lred[ty][ww][n];
      il[ty][ct] = 0.5f / s;
    }

  f32x4 xacc[2] = {fz, fz};
  float* attn = out1 + (size_t)bh * N_ * N_;
  const u16* vtb = vt + (size_t)bh * D_ * N_ + (size_t)(w * 16 + m16) * N_;

  // ---- loop 2: normalize, store attn, PV (single lP, 2 barriers/tile) ----
#pragma unroll
  for (int mt = 0; mt < 8; ++mt) {
    const int m0 = mt * 128;
#pragma unroll
    for (int ct = 0; ct < 2; ++ct) {
      union { uint2 u; u16 s[4]; } ur, uc, pk;
      ur.u = pst[0][mt][ct];
      uc.u = pst[1][mt][ct];
      f32x4 pv;
#pragma unroll
      for (int rg = 0; rg < 4; ++rg) {
        pv[rg] = bf2f(ur.s[rg]) * il[0][ct] + bf2f(uc.s[rg]) * il[1][ct];
        pk.s[rg] = f2bf(pv[rg]);
      }
      const int nrow = n0 + ct * 16 + m16;
      const int mcol = m0 + w * 16 + qd * 4;
      *(f32x4*)(attn + (size_t)nrow * N_ + mcol) = pv;
      *(uint2*)&lP[(ct * 16 + m16) * 136 + w * 16 + qd * 4] = pk.u;
    }
    __syncthreads();  // lP tile complete
#pragma unroll
    for (int ks = 0; ks < 4; ++ks) {
      bf16x8 pa[2];
#pragma unroll
      for (int ct = 0; ct < 2; ++ct)
        pa[ct] = ld_frag(&lP[(ct * 16 + m16) * 136 + ks * 32 + qd * 8]);
      bf16x8 vb = ld_frag(vtb + m0 + ks * 32 + qd * 8);
#pragma unroll
      for (int ct = 0; ct < 2; ++ct)
        xacc[ct] = mfma16(pa[ct], vb, xacc[ct]);
    }
    __syncthreads();  // lP readers done -> next tile may overwrite
  }
  // epilogue: x -> out0 (N,B,C)
#pragma unroll
  for (int ct = 0; ct < 2; ++ct)
#pragma unroll
    for (int rg = 0; rg < 4; ++rg) {
      int n = n0 + ct * 16 + qd * 4 + rg;
      int d = w * 16 + m16;
      out0[((size_t)n * B_ + b) * C_ + h * 128 + d] = xacc[ct][rg];
    }
}

// ---------- launch ----------
extern "C" void kernel_launch(void* const* d_in, const int* in_sizes, int n_in,
                              void* d_out, int out_size, void* d_ws, size_t ws_size,
                              hipStream_t stream) {
  (void)in_sizes; (void)n_in; (void)out_size; (void)ws_size;
  const float* in_f[10];
  for (int i = 0; i < 10; ++i) in_f[i] = (const float*)d_in[i];

  u16* ws = (u16*)d_ws;
  u16* Xc[5], *Wc[5], *P[5];
  for (int i = 0; i < 5; ++i) Xc[i] = ws + (size_t)i * NB * C_;
  u16* wbase = ws + (size_t)5 * NB * C_;
  for (int i = 0; i < 5; ++i) Wc[i] = wbase + (size_t)i * C_ * C_;
  u16* pbase = wbase + (size_t)5 * C_ * C_;
  for (int i = 0; i < 5; ++i) P[i] = pbase + (size_t)i * BH * N_ * D_;
  u16* vt = pbase + (size_t)5 * BH * N_ * D_;

  float* out0 = (float*)d_out;
  float* out1 = out0 + (size_t)N_ * B_ * C_;

  ConvArgs ca;
  for (int i = 0; i < 5; ++i) { ca.s[i] = in_f[i];     ca.d[i] = Xc[i];  ca.n[i] = NB * C_; }
  for (int i = 0; i < 5; ++i) { ca.s[5+i] = in_f[5+i]; ca.d[5+i] = Wc[i]; ca.n[5+i] = C_ * C_; }
  k_convert<<<dim3(2048, 10), 256, 0, stream>>>(ca);

  ProjArgs pa;
  for (int i = 0; i < 5; ++i) { pa.X[i] = Xc[i]; pa.W[i] = Wc[i]; pa.O[i] = P[i]; }
  k_proj<<<dim3(C_ / 128, NB / 128, 5), 256, 0, stream>>>(pa);

  k_transpose<<<dim3(N_ / 64, BH), 256, 0, stream>>>(P[4], vt);

  k_attn<<<dim3(N_ / 32, BH), 512, 0, stream>>>(P[0], P[1], P[2], P[3], vt, out0, out1);
}